// Round 13
// baseline (189.963 us; speedup 1.0000x reference)
//
#include <hip/hip_runtime.h>
#include <hip/hip_bf16.h>
#include <math.h>

#define N_NODES 50000
#define N_EDGES 800000
#define NBUCKET 196              // ceil(50000/256)
#define PART_E  4096             // edges per part1 block
#define GEMM_BLOCKS 625          // N_NODES / 80
#define SORT_BLOCKS 784
#define SORT_CHUNK  1021         // ceil(N_EDGES / SORT_BLOCKS)

typedef unsigned short u16;
typedef unsigned int   u32;
typedef short short8 __attribute__((ext_vector_type(8)));
typedef float f32x4  __attribute__((ext_vector_type(4)));

static __device__ __forceinline__ float b2f(u16 u) {
    union { u32 i; float f; } x; x.i = ((u32)u) << 16; return x.f;
}
static __device__ __forceinline__ u16 f2b(float f) {
    union { float f; u32 i; } x; x.f = f;
    u32 r = x.i + 0x7fffu + ((x.i >> 16) & 1u);   // round-to-nearest-even
    return (u16)(r >> 16);
}

// ---------------------------------------------------------------------------
// prep: blocks [0,49) zero cnt; blocks [49,241) transpose weights to bf16.
// ---------------------------------------------------------------------------
__global__ __launch_bounds__(256) void k_prep(
    const float* __restrict__ Wp1, const float* __restrict__ Ws1,
    const float* __restrict__ Wp2, const float* __restrict__ Ws2,
    u16* __restrict__ WT1p, u16* __restrict__ WT1s,
    u16* __restrict__ WT2p, u16* __restrict__ WT2s,
    int* __restrict__ cnt)
{
    const int b = blockIdx.x, t = threadIdx.x;
    if (b < 49) {
        const int i = b * 256 + t;
        if (i < 12500) reinterpret_cast<int4*>(cnt)[i] = make_int4(0, 0, 0, 0);
        return;
    }
    const int idx = (b - 49) * 2 + (t >> 7);   // [0,384)
    const int k = t & 127;
    const float* src; u16* dst; int N, n;
    if (idx < 128)      { src = Wp1; N = 128; n = idx;       dst = WT1p + n * 128; }
    else if (idx < 256) { src = Ws1; N = 128; n = idx - 128; dst = WT1s + n * 128; }
    else if (idx < 320) { src = Wp2; N = 64;  n = idx - 256; dst = WT2p + n * 128; }
    else                { src = Ws2; N = 64;  n = idx - 320; dst = WT2s + n * 128; }
    dst[k] = f2b(src[k * N + n]);
}

// ---------------------------------------------------------------------------
// hist: per-row counts, int4-vectorized er reads (4 edges/thread).
// ---------------------------------------------------------------------------
__global__ __launch_bounds__(256) void k_hist(
    const int* __restrict__ er, int* __restrict__ cnt)
{
    const int g4 = blockIdx.x * 256 + threadIdx.x;
    if (g4 < N_EDGES / 4) {
        const int4 v = reinterpret_cast<const int4*>(er)[g4];
        atomicAdd(&cnt[v.x], 1);
        atomicAdd(&cnt[v.y], 1);
        atomicAdd(&cnt[v.z], 1);
        atomicAdd(&cnt[v.w], 1);
    }
}

__global__ __launch_bounds__(256) void k_scan1(
    const int* __restrict__ cnt, int* __restrict__ rowptr, int* __restrict__ bsum)
{
    __shared__ int wsum[4];
    const int t = threadIdx.x;
    const int g4 = blockIdx.x * 256 + t;
    int4 v = make_int4(0, 0, 0, 0);
    if (g4 < 12500) v = reinterpret_cast<const int4*>(cnt)[g4];
    const int s0 = v.x, s1 = s0 + v.y, s2 = s1 + v.z, s3 = s2 + v.w;

    const int lane = t & 63, wv = t >> 6;
    int incl = s3;
#pragma unroll
    for (int off = 1; off < 64; off <<= 1) {
        int u = __shfl_up(incl, off, 64);
        if (lane >= off) incl += u;
    }
    if (lane == 63) wsum[wv] = incl;
    __syncthreads();
    int woff = 0;
    if (wv > 0) woff += wsum[0];
    if (wv > 1) woff += wsum[1];
    if (wv > 2) woff += wsum[2];
    const int excl = woff + incl - s3;

    if (g4 < 12500) {
        int4 o;
        o.x = excl + s0; o.y = excl + s1; o.z = excl + s2; o.w = excl + s3;
        reinterpret_cast<int4*>(rowptr + 1)[g4] = o;
    }
    if (t == 255) bsum[blockIdx.x] = woff + incl;
}

// scan3: add block offsets; emit bucket cursors cur[k] = rowptr[k*256] and
// per-row scatter cursors rowcur[i] = rowptr[i].
__global__ __launch_bounds__(256) void k_scan3(
    int* __restrict__ rowptr, const int* __restrict__ bsum,
    int* __restrict__ cur, int* __restrict__ rowcur)
{
    __shared__ int s_add;
    const int b = blockIdx.x;
    const int t = threadIdx.x;
    if (t < 64) {
        int v = (t < b) ? bsum[t] : 0;
#pragma unroll
        for (int off = 32; off; off >>= 1) v += __shfl_xor(v, off, 64);
        if (t == 0) s_add = v;
    }
    __syncthreads();
    const int add = s_add;
    const int g4 = b * 256 + t;
    if (g4 < 12500) {
        int4* o4 = reinterpret_cast<int4*>(rowptr + 1);
        int4 v = o4[g4];
        v.x += add; v.y += add; v.z += add; v.w += add;
        if (b) o4[g4] = v;                      // b==0: add==0, skip write
        const int i0 = 4 * g4 + 1;
        const int vv[4] = {v.x, v.y, v.z, v.w};
#pragma unroll
        for (int j = 0; j < 4; ++j) {
            const int idx = i0 + j;
            if (idx < N_NODES) {
                rowcur[idx] = vv[j];
                if ((idx & 255) == 0) cur[idx >> 8] = vv[j];
            }
        }
    }
    if (b == 0 && t == 0) { rowptr[0] = 0; rowcur[0] = 0; cur[0] = 0; }
}

// ---------------------------------------------------------------------------
// FAT kernel: blocks [0,625) = GEMM1 (MFMA), blocks [625,821) = part1.
// ---------------------------------------------------------------------------
__global__ __launch_bounds__(256) void k_gemm1_part1(
    const float* __restrict__ X,
    const u16* __restrict__ WT1p, const u16* __restrict__ WT1s,
    const float* __restrict__ bp, const float* __restrict__ bs,
    u16* __restrict__ Y1pb, u16* __restrict__ ACC1b,
    const int* __restrict__ er, const int* __restrict__ ec,
    const float* __restrict__ ev,
    int* __restrict__ cur, uint2* __restrict__ parted)
{
    __shared__ u16 Xs[80 * 128];
    __shared__ int hist[NBUCKET], base[NBUCKET], cntl[NBUCKET];
    const int t = threadIdx.x;

    if (blockIdx.x >= GEMM_BLOCKS) {
        // ---- part1 (+pack) ----
        if (t < NBUCKET) hist[t] = 0;
        __syncthreads();

        const int e0 = (blockIdx.x - GEMM_BLOCKS) * PART_E;
        int rows[16]; u32 pks[16];
#pragma unroll
        for (int i = 0; i < 16; ++i) {
            const int e = e0 + t + 256 * i;
            if (e < N_EDGES) {
                rows[i] = er[e];
                pks[i] = (u32)ec[e] | ((u32)f2b(ev[e]) << 16);
                atomicAdd(&hist[rows[i] >> 8], 1);
            } else rows[i] = -1;
        }
        __syncthreads();
        if (t < NBUCKET) { base[t] = atomicAdd(&cur[t], hist[t]); cntl[t] = 0; }
        __syncthreads();

#pragma unroll
        for (int i = 0; i < 16; ++i) {
            if (rows[i] >= 0) {
                const int b = rows[i] >> 8;
                const int off = atomicAdd(&cntl[b], 1);
                parted[base[b] + off] = make_uint2(pks[i], (u32)rows[i]);
            }
        }
        return;
    }

    // ---- GEMM1 ----
    const float4* Xv = reinterpret_cast<const float4*>(X) + (size_t)blockIdx.x * 2560;
#pragma unroll
    for (int i = 0; i < 10; ++i) {
        const int f4 = t + 256 * i;
        const float4 v = Xv[f4];
        const int row = f4 >> 5, col4 = f4 & 31;
        const u32 lo = (u32)f2b(v.x) | ((u32)f2b(v.y) << 16);
        const u32 hi = (u32)f2b(v.z) | ((u32)f2b(v.w) << 16);
        const int e = row * 128 + ((col4 * 4) ^ ((row & 7) << 3));
        *reinterpret_cast<uint2*>(&Xs[e]) = make_uint2(lo, hi);
    }
    __syncthreads();

    const int lane = t & 63;
    const int w = t >> 6;
    const int mat = w >> 1;
    const int cbase = (w & 1) * 64;
    const u16* __restrict__ WT = mat ? WT1s : WT1p;
    const int lr = lane & 15;
    const int lk = (lane >> 4) * 8;

    f32x4 acc[5][4];
#pragma unroll
    for (int m = 0; m < 5; ++m)
#pragma unroll
        for (int n = 0; n < 4; ++n) acc[m][n] = (f32x4){0.f, 0.f, 0.f, 0.f};

#pragma unroll
    for (int kk = 0; kk < 4; ++kk) {
        short8 b[4];
#pragma unroll
        for (int n = 0; n < 4; ++n) {
            const int col = cbase + n * 16 + lr;
            b[n] = *reinterpret_cast<const short8*>(WT + col * 128 + kk * 32 + lk);
        }
#pragma unroll
        for (int m = 0; m < 5; ++m) {
            const int row = m * 16 + lr;
            const int e = row * 128 + ((kk * 32 + lk) ^ ((row & 7) << 3));
            const short8 a = *reinterpret_cast<const short8*>(&Xs[e]);
#pragma unroll
            for (int n = 0; n < 4; ++n)
                acc[m][n] = __builtin_amdgcn_mfma_f32_16x16x32_bf16(a, b[n], acc[m][n], 0, 0, 0);
        }
    }

    const int row0 = blockIdx.x * 80;
    const int rq = (lane >> 4) * 4;
    if (mat == 0) {
#pragma unroll
        for (int m = 0; m < 5; ++m)
#pragma unroll
            for (int n = 0; n < 4; ++n) {
                const int col = cbase + n * 16 + lr;
#pragma unroll
                for (int q = 0; q < 4; ++q)
                    Y1pb[(size_t)(row0 + m * 16 + rq + q) * 128 + col] = f2b(acc[m][n][q]);
            }
    } else {
        float bias[4];
#pragma unroll
        for (int n = 0; n < 4; ++n) {
            const int col = cbase + n * 16 + lr;
            bias[n] = bs[col] + bp[col];
        }
#pragma unroll
        for (int m = 0; m < 5; ++m)
#pragma unroll
            for (int n = 0; n < 4; ++n) {
                const int col = cbase + n * 16 + lr;
#pragma unroll
                for (int q = 0; q < 4; ++q)
                    ACC1b[(size_t)(row0 + m * 16 + rq + q) * 128 + col] = f2b(acc[m][n][q] + bias[n]);
            }
    }
}

// ---------------------------------------------------------------------------
// sort2 v2: 784 blocks, each owns a contiguous 1021-edge chunk of parted
// (chunks lie within ~one bucket -> ecv32 writes stay window-local).
// Slot assignment via global per-row cursors rowcur (init'd by scan3).
// ---------------------------------------------------------------------------
__global__ __launch_bounds__(256) void k_sort2(
    const uint2* __restrict__ parted, int* __restrict__ rowcur,
    u32* __restrict__ ecv32)
{
    const int b = blockIdx.x;
    const int t = threadIdx.x;
    const int lo = b * SORT_CHUNK;
    int hi = lo + SORT_CHUNK;
    if (hi > N_EDGES) hi = N_EDGES;

    for (int e = lo + t; e < hi; e += 256) {
        const uint2 pe = parted[e];
        const int slot = atomicAdd(&rowcur[pe.y], 1);
        ecv32[slot] = pe.x;
    }
}

// ---------------------------------------------------------------------------
// agg1: H1b[i] = relu( ACC1b[i] + sum val_j * Y1pb[col_j] )    (bf16 out)
// one wave per node; 8 in-flight row-gathers (MLP=8).
// ---------------------------------------------------------------------------
__global__ __launch_bounds__(256) void k_agg1(
    const int* __restrict__ rowptr, const u32* __restrict__ ecv32,
    const u16* __restrict__ Y1pb, const u16* __restrict__ ACC1b,
    u16* __restrict__ H1b)
{
    const unsigned tid = blockIdx.x * 256u + threadIdx.x;
    const unsigned i = tid >> 6;
    if (i >= N_NODES) return;
    const unsigned lane = tid & 63u;

    const int e0 = rowptr[i];
    const int e1 = rowptr[i + 1];

    const u32 s = reinterpret_cast<const u32*>(ACC1b)[i * 64 + lane];

    const u32* __restrict__ Yv = reinterpret_cast<const u32*>(Y1pb);

    float ax0 = 0.f, ay0 = 0.f, ax1 = 0.f, ay1 = 0.f;
    float ax2 = 0.f, ay2 = 0.f, ax3 = 0.f, ay3 = 0.f;
    int j = e0;
    for (; j + 7 < e1; j += 8) {
        u32 p[8], w[8];
#pragma unroll
        for (int q = 0; q < 8; ++q) p[q] = ecv32[j + q];
#pragma unroll
        for (int q = 0; q < 8; ++q) w[q] = Yv[(p[q] & 0xffffu) * 64 + lane];
#pragma unroll
        for (int q = 0; q < 8; ++q) {
            const float v = b2f((u16)(p[q] >> 16));
            if ((q & 3) == 0) { ax0 = fmaf(v, b2f((u16)(w[q] & 0xffffu)), ax0); ay0 = fmaf(v, b2f((u16)(w[q] >> 16)), ay0); }
            if ((q & 3) == 1) { ax1 = fmaf(v, b2f((u16)(w[q] & 0xffffu)), ax1); ay1 = fmaf(v, b2f((u16)(w[q] >> 16)), ay1); }
            if ((q & 3) == 2) { ax2 = fmaf(v, b2f((u16)(w[q] & 0xffffu)), ax2); ay2 = fmaf(v, b2f((u16)(w[q] >> 16)), ay2); }
            if ((q & 3) == 3) { ax3 = fmaf(v, b2f((u16)(w[q] & 0xffffu)), ax3); ay3 = fmaf(v, b2f((u16)(w[q] >> 16)), ay3); }
        }
    }
    for (; j + 3 < e1; j += 4) {
        const u32 p0 = ecv32[j], p1 = ecv32[j + 1], p2 = ecv32[j + 2], p3 = ecv32[j + 3];
        const u32 w0 = Yv[(p0 & 0xffffu) * 64 + lane];
        const u32 w1 = Yv[(p1 & 0xffffu) * 64 + lane];
        const u32 w2 = Yv[(p2 & 0xffffu) * 64 + lane];
        const u32 w3 = Yv[(p3 & 0xffffu) * 64 + lane];
        const float v0 = b2f((u16)(p0 >> 16)), v1 = b2f((u16)(p1 >> 16));
        const float v2 = b2f((u16)(p2 >> 16)), v3 = b2f((u16)(p3 >> 16));
        ax0 = fmaf(v0, b2f((u16)(w0 & 0xffffu)), ax0); ay0 = fmaf(v0, b2f((u16)(w0 >> 16)), ay0);
        ax1 = fmaf(v1, b2f((u16)(w1 & 0xffffu)), ax1); ay1 = fmaf(v1, b2f((u16)(w1 >> 16)), ay1);
        ax2 = fmaf(v2, b2f((u16)(w2 & 0xffffu)), ax2); ay2 = fmaf(v2, b2f((u16)(w2 >> 16)), ay2);
        ax3 = fmaf(v3, b2f((u16)(w3 & 0xffffu)), ax3); ay3 = fmaf(v3, b2f((u16)(w3 >> 16)), ay3);
    }
    for (; j < e1; ++j) {
        const u32 p = ecv32[j];
        const u32 w = Yv[(p & 0xffffu) * 64 + lane];
        const float v = b2f((u16)(p >> 16));
        ax0 = fmaf(v, b2f((u16)(w & 0xffffu)), ax0);
        ay0 = fmaf(v, b2f((u16)(w >> 16)), ay0);
    }
    const float ax = (ax0 + ax1) + (ax2 + ax3);
    const float ay = (ay0 + ay1) + (ay2 + ay3);

    const float h0 = fmaxf(b2f((u16)(s & 0xffffu)) + ax, 0.f);
    const float h1 = fmaxf(b2f((u16)(s >> 16)) + ay, 0.f);
    reinterpret_cast<u32*>(H1b)[i * 64 + lane] = (u32)f2b(h0) | ((u32)f2b(h1) << 16);
}

// ---------------------------------------------------------------------------
// GEMM2 (MFMA): Y2pb (bf16) = H1 @ Wp2 ; ACC2b (bf16) = H1 @ Ws2 + (bs2+bp2)
// ---------------------------------------------------------------------------
__global__ __launch_bounds__(256) void k_gemm2(
    const u16* __restrict__ H1b,
    const u16* __restrict__ WT2p, const u16* __restrict__ WT2s,
    const float* __restrict__ bp, const float* __restrict__ bs,
    u16* __restrict__ Y2pb, u16* __restrict__ ACC2b)
{
    __shared__ u16 Hs[80 * 128];
    const int t = threadIdx.x;

    const uint4* Hv = reinterpret_cast<const uint4*>(H1b) + (size_t)blockIdx.x * 1280;
#pragma unroll
    for (int i = 0; i < 5; ++i) {
        const int ch = t + 256 * i;
        const uint4 v = Hv[ch];
        const int row = ch >> 4, c16 = ch & 15;
        const int e = row * 128 + ((c16 * 8) ^ ((row & 7) << 3));
        *reinterpret_cast<uint4*>(&Hs[e]) = v;
    }
    __syncthreads();

    const int lane = t & 63;
    const int w = t >> 6;
    const int mat = w >> 1;
    const int cbase = (w & 1) * 32;
    const u16* __restrict__ WT = mat ? WT2s : WT2p;
    const int lr = lane & 15;
    const int lk = (lane >> 4) * 8;

    f32x4 acc[5][2];
#pragma unroll
    for (int m = 0; m < 5; ++m)
#pragma unroll
        for (int n = 0; n < 2; ++n) acc[m][n] = (f32x4){0.f, 0.f, 0.f, 0.f};

#pragma unroll
    for (int kk = 0; kk < 4; ++kk) {
        short8 b[2];
#pragma unroll
        for (int n = 0; n < 2; ++n) {
            const int col = cbase + n * 16 + lr;
            b[n] = *reinterpret_cast<const short8*>(WT + col * 128 + kk * 32 + lk);
        }
#pragma unroll
        for (int m = 0; m < 5; ++m) {
            const int row = m * 16 + lr;
            const int e = row * 128 + ((kk * 32 + lk) ^ ((row & 7) << 3));
            const short8 a = *reinterpret_cast<const short8*>(&Hs[e]);
#pragma unroll
            for (int n = 0; n < 2; ++n)
                acc[m][n] = __builtin_amdgcn_mfma_f32_16x16x32_bf16(a, b[n], acc[m][n], 0, 0, 0);
        }
    }

    const int row0 = blockIdx.x * 80;
    const int rq = (lane >> 4) * 4;
    if (mat == 0) {
#pragma unroll
        for (int m = 0; m < 5; ++m)
#pragma unroll
            for (int n = 0; n < 2; ++n) {
                const int col = cbase + n * 16 + lr;
#pragma unroll
                for (int q = 0; q < 4; ++q)
                    Y2pb[(size_t)(row0 + m * 16 + rq + q) * 64 + col] = f2b(acc[m][n][q]);
            }
    } else {
        float bias[2];
#pragma unroll
        for (int n = 0; n < 2; ++n) {
            const int col = cbase + n * 16 + lr;
            bias[n] = bs[col] + bp[col];
        }
#pragma unroll
        for (int m = 0; m < 5; ++m)
#pragma unroll
            for (int n = 0; n < 2; ++n) {
                const int col = cbase + n * 16 + lr;
#pragma unroll
                for (int q = 0; q < 4; ++q)
                    ACC2b[(size_t)(row0 + m * 16 + rq + q) * 64 + col] = f2b(acc[m][n][q] + bias[n]);
            }
    }
}

// ---------------------------------------------------------------------------
// agg2: H2b[i] = relu( ACC2b[i] + sum val_j * Y2pb[col_j] )   (bf16 out)
// 2 nodes per wave, 32 lanes/node; MLP=8.
// ---------------------------------------------------------------------------
__global__ __launch_bounds__(256) void k_agg2(
    const int* __restrict__ rowptr, const u32* __restrict__ ecv32,
    const u16* __restrict__ Y2pb, const u16* __restrict__ ACC2b,
    u16* __restrict__ H2b)
{
    const unsigned tid = blockIdx.x * 256u + threadIdx.x;
    const unsigned lane = tid & 63u;
    const unsigned i = (tid >> 6) * 2 + (lane >> 5);
    if (i >= N_NODES) return;
    const unsigned hl = lane & 31u;

    const int e0 = rowptr[i];
    const int e1 = rowptr[i + 1];

    const u32 s = reinterpret_cast<const u32*>(ACC2b)[i * 32 + hl];

    const u32* __restrict__ Yv = reinterpret_cast<const u32*>(Y2pb);

    float ax0 = 0.f, ay0 = 0.f, ax1 = 0.f, ay1 = 0.f;
    float ax2 = 0.f, ay2 = 0.f, ax3 = 0.f, ay3 = 0.f;
    int j = e0;
    for (; j + 7 < e1; j += 8) {
        u32 p[8], w[8];
#pragma unroll
        for (int q = 0; q < 8; ++q) p[q] = ecv32[j + q];
#pragma unroll
        for (int q = 0; q < 8; ++q) w[q] = Yv[(p[q] & 0xffffu) * 32 + hl];
#pragma unroll
        for (int q = 0; q < 8; ++q) {
            const float v = b2f((u16)(p[q] >> 16));
            if ((q & 3) == 0) { ax0 = fmaf(v, b2f((u16)(w[q] & 0xffffu)), ax0); ay0 = fmaf(v, b2f((u16)(w[q] >> 16)), ay0); }
            if ((q & 3) == 1) { ax1 = fmaf(v, b2f((u16)(w[q] & 0xffffu)), ax1); ay1 = fmaf(v, b2f((u16)(w[q] >> 16)), ay1); }
            if ((q & 3) == 2) { ax2 = fmaf(v, b2f((u16)(w[q] & 0xffffu)), ax2); ay2 = fmaf(v, b2f((u16)(w[q] >> 16)), ay2); }
            if ((q & 3) == 3) { ax3 = fmaf(v, b2f((u16)(w[q] & 0xffffu)), ax3); ay3 = fmaf(v, b2f((u16)(w[q] >> 16)), ay3); }
        }
    }
    for (; j + 3 < e1; j += 4) {
        const u32 p0 = ecv32[j], p1 = ecv32[j + 1], p2 = ecv32[j + 2], p3 = ecv32[j + 3];
        const u32 w0 = Yv[(p0 & 0xffffu) * 32 + hl];
        const u32 w1 = Yv[(p1 & 0xffffu) * 32 + hl];
        const u32 w2 = Yv[(p2 & 0xffffu) * 32 + hl];
        const u32 w3 = Yv[(p3 & 0xffffu) * 32 + hl];
        const float v0 = b2f((u16)(p0 >> 16)), v1 = b2f((u16)(p1 >> 16));
        const float v2 = b2f((u16)(p2 >> 16)), v3 = b2f((u16)(p3 >> 16));
        ax0 = fmaf(v0, b2f((u16)(w0 & 0xffffu)), ax0); ay0 = fmaf(v0, b2f((u16)(w0 >> 16)), ay0);
        ax1 = fmaf(v1, b2f((u16)(w1 & 0xffffu)), ax1); ay1 = fmaf(v1, b2f((u16)(w1 >> 16)), ay1);
        ax2 = fmaf(v2, b2f((u16)(w2 & 0xffffu)), ax2); ay2 = fmaf(v2, b2f((u16)(w2 >> 16)), ay2);
        ax3 = fmaf(v3, b2f((u16)(w3 & 0xffffu)), ax3); ay3 = fmaf(v3, b2f((u16)(w3 >> 16)), ay3);
    }
    for (; j < e1; ++j) {
        const u32 p = ecv32[j];
        const u32 w = Yv[(p & 0xffffu) * 32 + hl];
        const float v = b2f((u16)(p >> 16));
        ax0 = fmaf(v, b2f((u16)(w & 0xffffu)), ax0);
        ay0 = fmaf(v, b2f((u16)(w >> 16)), ay0);
    }
    const float ax = (ax0 + ax1) + (ax2 + ax3);
    const float ay = (ay0 + ay1) + (ay2 + ay3);

    const float h0 = fmaxf(b2f((u16)(s & 0xffffu)) + ax, 0.f);
    const float h1 = fmaxf(b2f((u16)(s >> 16)) + ay, 0.f);
    reinterpret_cast<u32*>(H2b)[i * 32 + hl] = (u32)f2b(h0) | ((u32)f2b(h1) << 16);
}

// ---------------------------------------------------------------------------
// edgedot: out[e] = sigmoid( dot(H2[row], H2[col]) )
// one THREAD per edge: 8x uint4 dual loads, 64-FMA register dot.
// ---------------------------------------------------------------------------
__global__ __launch_bounds__(256) void k_edgedot(
    const int* __restrict__ er, const int* __restrict__ ec,
    const u16* __restrict__ H2b, float* __restrict__ out)
{
    const int e = blockIdx.x * 256 + threadIdx.x;
    if (e >= N_EDGES) return;

    const int r = er[e];
    const int c = ec[e];

    const uint4* __restrict__ A = reinterpret_cast<const uint4*>(H2b + (size_t)r * 64);
    const uint4* __restrict__ B = reinterpret_cast<const uint4*>(H2b + (size_t)c * 64);

    float s0 = 0.f, s1 = 0.f, s2 = 0.f, s3 = 0.f;
#pragma unroll
    for (int k = 0; k < 8; ++k) {
        const uint4 a = A[k];
        const uint4 b = B[k];
        s0 = fmaf(b2f((u16)(a.x & 0xffffu)), b2f((u16)(b.x & 0xffffu)), s0);
        s1 = fmaf(b2f((u16)(a.x >> 16)),     b2f((u16)(b.x >> 16)),     s1);
        s2 = fmaf(b2f((u16)(a.y & 0xffffu)), b2f((u16)(b.y & 0xffffu)), s2);
        s3 = fmaf(b2f((u16)(a.y >> 16)),     b2f((u16)(b.y >> 16)),     s3);
        s0 = fmaf(b2f((u16)(a.z & 0xffffu)), b2f((u16)(b.z & 0xffffu)), s0);
        s1 = fmaf(b2f((u16)(a.z >> 16)),     b2f((u16)(b.z >> 16)),     s1);
        s2 = fmaf(b2f((u16)(a.w & 0xffffu)), b2f((u16)(b.w & 0xffffu)), s2);
        s3 = fmaf(b2f((u16)(a.w >> 16)),     b2f((u16)(b.w >> 16)),     s3);
    }
    const float p = (s0 + s1) + (s2 + s3);
    out[e] = 1.f / (1.f + expf(-p));
}

// ---------------------------------------------------------------------------
extern "C" void kernel_launch(void* const* d_in, const int* in_sizes, int n_in,
                              void* d_out, int out_size, void* d_ws, size_t ws_size,
                              hipStream_t stream)
{
    const float* X   = (const float*)d_in[0];
    const int*   er  = (const int*)d_in[1];
    const int*   ec  = (const int*)d_in[2];
    const float* ev  = (const float*)d_in[3];
    const float* Wp1 = (const float*)d_in[4];
    const float* bp1 = (const float*)d_in[5];
    const float* Ws1 = (const float*)d_in[6];
    const float* bs1 = (const float*)d_in[7];
    const float* Wp2 = (const float*)d_in[8];
    const float* bp2 = (const float*)d_in[9];
    const float* Ws2 = (const float*)d_in[10];
    const float* bs2 = (const float*)d_in[11];
    float* out = (float*)d_out;

    // workspace layout (float units from base):
    //   phase 1: ACC1b bf16 [0, 3.2M) | Y1pb bf16 [3.2M, 6.4M) | H1b bf16 [6.4M, 9.6M)
    //   phase 2 (reuses [0,4.8M)): Y2pb [0,1.6M) | ACC2b [1.6M,3.2M) | H2b [3.2M,4.8M)
    //   CSR at [9.6M,...): rp_base[50008] | bsum[64] | cur[256] | rowcur[50000]
    //     | ecv32 u32[800k] | WT bufs | parted uint2[800k].
    //   cnt[50000] aliases ecv32 (dead before sort2).
    float* ws     = (float*)d_ws;
    u16*   ACC1b  = (u16*)ws;
    u16*   Y1pb   = (u16*)(ws + (size_t)3200000);
    u16*   H1b    = (u16*)(ws + (size_t)6400000);
    u16*   Y2pb   = (u16*)ws;
    u16*   ACC2b  = (u16*)(ws + (size_t)1600000);
    u16*   H2b    = (u16*)(ws + (size_t)3200000);

    int*  rp_base = (int*)(ws + (size_t)9600000);
    int*  rowptr  = rp_base + 3;          // rowptr+1 is 16B-aligned
    int*  bsum    = rp_base + 50008;      // 16B-aligned
    int*  cur     = bsum + 64;
    int*  rowcur  = cur + 256;            // 16B-aligned
    u32*  ecv32   = (u32*)(rowcur + 50000);   // 16B-aligned
    int*  cnt     = (int*)ecv32;          // alias (dead before sort2)
    u16*  WT1p    = (u16*)(ecv32 + N_EDGES);
    u16*  WT1s    = WT1p + 128 * 128;
    u16*  WT2p    = WT1s + 128 * 128;
    u16*  WT2s    = WT2p + 64 * 128;
    uint2* parted = (uint2*)(WT2s + 64 * 128);   // 16B-aligned (even u16 count)

    const dim3 blk(256);
    const int node_waves  = (N_NODES * 64 + 255) / 256;        // 12500
    const int node2_waves = ((N_NODES / 2) * 64 + 255) / 256;  // 6250
    const int edge_thr    = (N_EDGES + 255) / 256;             // 3125
    const int hist_blocks = (N_EDGES / 4 + 255) / 256;         // 782
    const int scan_blocks = 49;
    const int part_blocks = (N_EDGES + PART_E - 1) / PART_E;   // 196
    const int fat_blocks  = GEMM_BLOCKS + part_blocks;         // 821

    // prep (zero + weight transpose) + CSR build
    k_prep    <<<241,         blk, 0, stream>>>(Wp1, Ws1, Wp2, Ws2,
                                                WT1p, WT1s, WT2p, WT2s, cnt);
    k_hist    <<<hist_blocks, blk, 0, stream>>>(er, cnt);
    k_scan1   <<<scan_blocks, blk, 0, stream>>>(cnt, rowptr, bsum);
    k_scan3   <<<scan_blocks, blk, 0, stream>>>(rowptr, bsum, cur, rowcur);

    // layer-1 GEMM co-resident with edge partition (+pack)
    k_gemm1_part1<<<fat_blocks, blk, 0, stream>>>(X, WT1p, WT1s, bp1, bs1,
                                                  Y1pb, ACC1b, er, ec, ev, cur, parted);
    k_sort2   <<<SORT_BLOCKS, blk, 0, stream>>>(parted, rowcur, ecv32);

    // layer 1 aggregation
    k_agg1 <<<node_waves,  blk, 0, stream>>>(rowptr, ecv32, Y1pb, ACC1b, H1b);

    // layer 2
    k_gemm2<<<GEMM_BLOCKS, blk, 0, stream>>>(H1b, WT2p, WT2s, bp2, bs2, Y2pb, ACC2b);
    k_agg2 <<<node2_waves, blk, 0, stream>>>(rowptr, ecv32, Y2pb, ACC2b, H2b);

    // edge scores
    k_edgedot<<<edge_thr, blk, 0, stream>>>(er, ec, H2b, out);
}

// Round 14
// 175.818 us; speedup vs baseline: 1.0804x; 1.0804x over previous
//
#include <hip/hip_runtime.h>
#include <hip/hip_bf16.h>
#include <math.h>

#define N_NODES 50000
#define N_EDGES 800000
#define NBUCKET 196              // ceil(50000/256)
#define PART_E  4096             // edges per part1 block
#define GEMM_BLOCKS 625          // N_NODES / 80

typedef unsigned short u16;
typedef unsigned int   u32;
typedef short short8 __attribute__((ext_vector_type(8)));
typedef float f32x4  __attribute__((ext_vector_type(4)));

static __device__ __forceinline__ float b2f(u16 u) {
    union { u32 i; float f; } x; x.i = ((u32)u) << 16; return x.f;
}
static __device__ __forceinline__ u16 f2b(float f) {
    union { float f; u32 i; } x; x.f = f;
    u32 r = x.i + 0x7fffu + ((x.i >> 16) & 1u);   // round-to-nearest-even
    return (u16)(r >> 16);
}

// ---------------------------------------------------------------------------
// prep: blocks [0,49) zero cnt; blocks [49,241) transpose weights to bf16.
// ---------------------------------------------------------------------------
__global__ __launch_bounds__(256) void k_prep(
    const float* __restrict__ Wp1, const float* __restrict__ Ws1,
    const float* __restrict__ Wp2, const float* __restrict__ Ws2,
    u16* __restrict__ WT1p, u16* __restrict__ WT1s,
    u16* __restrict__ WT2p, u16* __restrict__ WT2s,
    int* __restrict__ cnt)
{
    const int b = blockIdx.x, t = threadIdx.x;
    if (b < 49) {
        const int i = b * 256 + t;
        if (i < 12500) reinterpret_cast<int4*>(cnt)[i] = make_int4(0, 0, 0, 0);
        return;
    }
    const int idx = (b - 49) * 2 + (t >> 7);   // [0,384)
    const int k = t & 127;
    const float* src; u16* dst; int N, n;
    if (idx < 128)      { src = Wp1; N = 128; n = idx;       dst = WT1p + n * 128; }
    else if (idx < 256) { src = Ws1; N = 128; n = idx - 128; dst = WT1s + n * 128; }
    else if (idx < 320) { src = Wp2; N = 64;  n = idx - 256; dst = WT2p + n * 128; }
    else                { src = Ws2; N = 64;  n = idx - 320; dst = WT2s + n * 128; }
    dst[k] = f2b(src[k * N + n]);
}

// ---------------------------------------------------------------------------
// hist: per-row counts only (packing happens in part1).
// ---------------------------------------------------------------------------
__global__ __launch_bounds__(256) void k_hist(
    const int* __restrict__ er, int* __restrict__ cnt)
{
    const int e = blockIdx.x * 256 + threadIdx.x;
    if (e < N_EDGES) atomicAdd(&cnt[er[e]], 1);
}

__global__ __launch_bounds__(256) void k_scan1(
    const int* __restrict__ cnt, int* __restrict__ rowptr, int* __restrict__ bsum)
{
    __shared__ int wsum[4];
    const int t = threadIdx.x;
    const int g4 = blockIdx.x * 256 + t;
    int4 v = make_int4(0, 0, 0, 0);
    if (g4 < 12500) v = reinterpret_cast<const int4*>(cnt)[g4];
    const int s0 = v.x, s1 = s0 + v.y, s2 = s1 + v.z, s3 = s2 + v.w;

    const int lane = t & 63, wv = t >> 6;
    int incl = s3;
#pragma unroll
    for (int off = 1; off < 64; off <<= 1) {
        int u = __shfl_up(incl, off, 64);
        if (lane >= off) incl += u;
    }
    if (lane == 63) wsum[wv] = incl;
    __syncthreads();
    int woff = 0;
    if (wv > 0) woff += wsum[0];
    if (wv > 1) woff += wsum[1];
    if (wv > 2) woff += wsum[2];
    const int excl = woff + incl - s3;

    if (g4 < 12500) {
        int4 o;
        o.x = excl + s0; o.y = excl + s1; o.z = excl + s2; o.w = excl + s3;
        reinterpret_cast<int4*>(rowptr + 1)[g4] = o;
    }
    if (t == 255) bsum[blockIdx.x] = woff + incl;
}

// scan3: add block offsets; also emit bucket cursors cur[k] = rowptr[k*256].
__global__ __launch_bounds__(256) void k_scan3(
    int* __restrict__ rowptr, const int* __restrict__ bsum, int* __restrict__ cur)
{
    __shared__ int s_add;
    const int b = blockIdx.x;
    const int t = threadIdx.x;
    if (t < 64) {
        int v = (t < b) ? bsum[t] : 0;
#pragma unroll
        for (int off = 32; off; off >>= 1) v += __shfl_xor(v, off, 64);
        if (t == 0) s_add = v;
    }
    __syncthreads();
    const int add = s_add;
    const int g4 = b * 256 + t;
    if (g4 < 12500) {
        int4* o4 = reinterpret_cast<int4*>(rowptr + 1);
        int4 v = o4[g4];
        v.x += add; v.y += add; v.z += add; v.w += add;
        if (b) o4[g4] = v;                      // b==0: add==0, skip write
        const int i0 = 4 * g4 + 1;
        const int vv[4] = {v.x, v.y, v.z, v.w};
#pragma unroll
        for (int j = 0; j < 4; ++j) {
            const int idx = i0 + j;
            if (idx < N_NODES && (idx & 255) == 0) cur[idx >> 8] = vv[j];
        }
    }
    if (b == 0 && t == 0) { rowptr[0] = 0; cur[0] = 0; }
}

// ---------------------------------------------------------------------------
// FAT kernel: blocks [0,625) = GEMM1 (MFMA), blocks [625,821) = part1.
// ---------------------------------------------------------------------------
__global__ __launch_bounds__(256) void k_gemm1_part1(
    const float* __restrict__ X,
    const u16* __restrict__ WT1p, const u16* __restrict__ WT1s,
    const float* __restrict__ bp, const float* __restrict__ bs,
    u16* __restrict__ Y1pb, u16* __restrict__ ACC1b,
    const int* __restrict__ er, const int* __restrict__ ec,
    const float* __restrict__ ev,
    int* __restrict__ cur, uint2* __restrict__ parted)
{
    __shared__ u16 Xs[80 * 128];
    __shared__ int hist[NBUCKET], base[NBUCKET], cntl[NBUCKET];
    const int t = threadIdx.x;

    if (blockIdx.x >= GEMM_BLOCKS) {
        // ---- part1 (+pack) ----
        if (t < NBUCKET) hist[t] = 0;
        __syncthreads();

        const int e0 = (blockIdx.x - GEMM_BLOCKS) * PART_E;
        int rows[16]; u32 pks[16];
#pragma unroll
        for (int i = 0; i < 16; ++i) {
            const int e = e0 + t + 256 * i;
            if (e < N_EDGES) {
                rows[i] = er[e];
                pks[i] = (u32)ec[e] | ((u32)f2b(ev[e]) << 16);
                atomicAdd(&hist[rows[i] >> 8], 1);
            } else rows[i] = -1;
        }
        __syncthreads();
        if (t < NBUCKET) { base[t] = atomicAdd(&cur[t], hist[t]); cntl[t] = 0; }
        __syncthreads();

#pragma unroll
        for (int i = 0; i < 16; ++i) {
            if (rows[i] >= 0) {
                const int b = rows[i] >> 8;
                const int off = atomicAdd(&cntl[b], 1);
                parted[base[b] + off] = make_uint2(pks[i], (u32)rows[i]);
            }
        }
        return;
    }

    // ---- GEMM1 ----
    const float4* Xv = reinterpret_cast<const float4*>(X) + (size_t)blockIdx.x * 2560;
#pragma unroll
    for (int i = 0; i < 10; ++i) {
        const int f4 = t + 256 * i;
        const float4 v = Xv[f4];
        const int row = f4 >> 5, col4 = f4 & 31;
        const u32 lo = (u32)f2b(v.x) | ((u32)f2b(v.y) << 16);
        const u32 hi = (u32)f2b(v.z) | ((u32)f2b(v.w) << 16);
        const int e = row * 128 + ((col4 * 4) ^ ((row & 7) << 3));
        *reinterpret_cast<uint2*>(&Xs[e]) = make_uint2(lo, hi);
    }
    __syncthreads();

    const int lane = t & 63;
    const int w = t >> 6;
    const int mat = w >> 1;
    const int cbase = (w & 1) * 64;
    const u16* __restrict__ WT = mat ? WT1s : WT1p;
    const int lr = lane & 15;
    const int lk = (lane >> 4) * 8;

    f32x4 acc[5][4];
#pragma unroll
    for (int m = 0; m < 5; ++m)
#pragma unroll
        for (int n = 0; n < 4; ++n) acc[m][n] = (f32x4){0.f, 0.f, 0.f, 0.f};

#pragma unroll
    for (int kk = 0; kk < 4; ++kk) {
        short8 b[4];
#pragma unroll
        for (int n = 0; n < 4; ++n) {
            const int col = cbase + n * 16 + lr;
            b[n] = *reinterpret_cast<const short8*>(WT + col * 128 + kk * 32 + lk);
        }
#pragma unroll
        for (int m = 0; m < 5; ++m) {
            const int row = m * 16 + lr;
            const int e = row * 128 + ((kk * 32 + lk) ^ ((row & 7) << 3));
            const short8 a = *reinterpret_cast<const short8*>(&Xs[e]);
#pragma unroll
            for (int n = 0; n < 4; ++n)
                acc[m][n] = __builtin_amdgcn_mfma_f32_16x16x32_bf16(a, b[n], acc[m][n], 0, 0, 0);
        }
    }

    const int row0 = blockIdx.x * 80;
    const int rq = (lane >> 4) * 4;
    if (mat == 0) {
#pragma unroll
        for (int m = 0; m < 5; ++m)
#pragma unroll
            for (int n = 0; n < 4; ++n) {
                const int col = cbase + n * 16 + lr;
#pragma unroll
                for (int q = 0; q < 4; ++q)
                    Y1pb[(size_t)(row0 + m * 16 + rq + q) * 128 + col] = f2b(acc[m][n][q]);
            }
    } else {
        float bias[4];
#pragma unroll
        for (int n = 0; n < 4; ++n) {
            const int col = cbase + n * 16 + lr;
            bias[n] = bs[col] + bp[col];
        }
#pragma unroll
        for (int m = 0; m < 5; ++m)
#pragma unroll
            for (int n = 0; n < 4; ++n) {
                const int col = cbase + n * 16 + lr;
#pragma unroll
                for (int q = 0; q < 4; ++q)
                    ACC1b[(size_t)(row0 + m * 16 + rq + q) * 128 + col] = f2b(acc[m][n][q] + bias[n]);
            }
    }
}

// pass 2: one block per bucket; scatter confined to the bucket's CSR window.
__global__ __launch_bounds__(256) void k_sort2(
    const int* __restrict__ rowptr, const uint2* __restrict__ parted,
    u32* __restrict__ ecv32)
{
    __shared__ int cur[256];
    const int b = blockIdx.x;
    const int t = threadIdx.x;
    const int r0 = b * 256;
    const int rt = r0 + t;
    cur[t] = rowptr[rt < N_NODES ? rt : N_NODES];
    __syncthreads();

    const int lo = rowptr[r0];
    const int r1 = r0 + 256;
    const int hi = rowptr[r1 < N_NODES ? r1 : N_NODES];

    for (int e = lo + t; e < hi; e += 256) {
        const uint2 pe = parted[e];
        const int low = (int)(pe.y & 255u);
        const int slot = atomicAdd(&cur[low], 1);
        ecv32[slot] = pe.x;
    }
}

// ---------------------------------------------------------------------------
// agg1: H1b[i] = relu( ACC1b[i] + sum val_j * Y1pb[col_j] )    (bf16 out)
// one wave per node; 8 in-flight row-gathers (MLP=8).
// ---------------------------------------------------------------------------
__global__ __launch_bounds__(256) void k_agg1(
    const int* __restrict__ rowptr, const u32* __restrict__ ecv32,
    const u16* __restrict__ Y1pb, const u16* __restrict__ ACC1b,
    u16* __restrict__ H1b)
{
    const unsigned tid = blockIdx.x * 256u + threadIdx.x;
    const unsigned i = tid >> 6;
    if (i >= N_NODES) return;
    const unsigned lane = tid & 63u;

    const int e0 = rowptr[i];
    const int e1 = rowptr[i + 1];

    const u32 s = reinterpret_cast<const u32*>(ACC1b)[i * 64 + lane];

    const u32* __restrict__ Yv = reinterpret_cast<const u32*>(Y1pb);

    float ax0 = 0.f, ay0 = 0.f, ax1 = 0.f, ay1 = 0.f;
    float ax2 = 0.f, ay2 = 0.f, ax3 = 0.f, ay3 = 0.f;
    int j = e0;
    for (; j + 7 < e1; j += 8) {
        u32 p[8], w[8];
#pragma unroll
        for (int q = 0; q < 8; ++q) p[q] = ecv32[j + q];
#pragma unroll
        for (int q = 0; q < 8; ++q) w[q] = Yv[(p[q] & 0xffffu) * 64 + lane];
#pragma unroll
        for (int q = 0; q < 8; ++q) {
            const float v = b2f((u16)(p[q] >> 16));
            if ((q & 3) == 0) { ax0 = fmaf(v, b2f((u16)(w[q] & 0xffffu)), ax0); ay0 = fmaf(v, b2f((u16)(w[q] >> 16)), ay0); }
            if ((q & 3) == 1) { ax1 = fmaf(v, b2f((u16)(w[q] & 0xffffu)), ax1); ay1 = fmaf(v, b2f((u16)(w[q] >> 16)), ay1); }
            if ((q & 3) == 2) { ax2 = fmaf(v, b2f((u16)(w[q] & 0xffffu)), ax2); ay2 = fmaf(v, b2f((u16)(w[q] >> 16)), ay2); }
            if ((q & 3) == 3) { ax3 = fmaf(v, b2f((u16)(w[q] & 0xffffu)), ax3); ay3 = fmaf(v, b2f((u16)(w[q] >> 16)), ay3); }
        }
    }
    for (; j + 3 < e1; j += 4) {
        const u32 p0 = ecv32[j], p1 = ecv32[j + 1], p2 = ecv32[j + 2], p3 = ecv32[j + 3];
        const u32 w0 = Yv[(p0 & 0xffffu) * 64 + lane];
        const u32 w1 = Yv[(p1 & 0xffffu) * 64 + lane];
        const u32 w2 = Yv[(p2 & 0xffffu) * 64 + lane];
        const u32 w3 = Yv[(p3 & 0xffffu) * 64 + lane];
        const float v0 = b2f((u16)(p0 >> 16)), v1 = b2f((u16)(p1 >> 16));
        const float v2 = b2f((u16)(p2 >> 16)), v3 = b2f((u16)(p3 >> 16));
        ax0 = fmaf(v0, b2f((u16)(w0 & 0xffffu)), ax0); ay0 = fmaf(v0, b2f((u16)(w0 >> 16)), ay0);
        ax1 = fmaf(v1, b2f((u16)(w1 & 0xffffu)), ax1); ay1 = fmaf(v1, b2f((u16)(w1 >> 16)), ay1);
        ax2 = fmaf(v2, b2f((u16)(w2 & 0xffffu)), ax2); ay2 = fmaf(v2, b2f((u16)(w2 >> 16)), ay2);
        ax3 = fmaf(v3, b2f((u16)(w3 & 0xffffu)), ax3); ay3 = fmaf(v3, b2f((u16)(w3 >> 16)), ay3);
    }
    for (; j < e1; ++j) {
        const u32 p = ecv32[j];
        const u32 w = Yv[(p & 0xffffu) * 64 + lane];
        const float v = b2f((u16)(p >> 16));
        ax0 = fmaf(v, b2f((u16)(w & 0xffffu)), ax0);
        ay0 = fmaf(v, b2f((u16)(w >> 16)), ay0);
    }
    const float ax = (ax0 + ax1) + (ax2 + ax3);
    const float ay = (ay0 + ay1) + (ay2 + ay3);

    const float h0 = fmaxf(b2f((u16)(s & 0xffffu)) + ax, 0.f);
    const float h1 = fmaxf(b2f((u16)(s >> 16)) + ay, 0.f);
    reinterpret_cast<u32*>(H1b)[i * 64 + lane] = (u32)f2b(h0) | ((u32)f2b(h1) << 16);
}

// ---------------------------------------------------------------------------
// GEMM2 (MFMA): Y2pb (bf16) = H1 @ Wp2 ; ACC2b (bf16) = H1 @ Ws2 + (bs2+bp2)
// ---------------------------------------------------------------------------
__global__ __launch_bounds__(256) void k_gemm2(
    const u16* __restrict__ H1b,
    const u16* __restrict__ WT2p, const u16* __restrict__ WT2s,
    const float* __restrict__ bp, const float* __restrict__ bs,
    u16* __restrict__ Y2pb, u16* __restrict__ ACC2b)
{
    __shared__ u16 Hs[80 * 128];
    const int t = threadIdx.x;

    const uint4* Hv = reinterpret_cast<const uint4*>(H1b) + (size_t)blockIdx.x * 1280;
#pragma unroll
    for (int i = 0; i < 5; ++i) {
        const int ch = t + 256 * i;
        const uint4 v = Hv[ch];
        const int row = ch >> 4, c16 = ch & 15;
        const int e = row * 128 + ((c16 * 8) ^ ((row & 7) << 3));
        *reinterpret_cast<uint4*>(&Hs[e]) = v;
    }
    __syncthreads();

    const int lane = t & 63;
    const int w = t >> 6;
    const int mat = w >> 1;
    const int cbase = (w & 1) * 32;
    const u16* __restrict__ WT = mat ? WT2s : WT2p;
    const int lr = lane & 15;
    const int lk = (lane >> 4) * 8;

    f32x4 acc[5][2];
#pragma unroll
    for (int m = 0; m < 5; ++m)
#pragma unroll
        for (int n = 0; n < 2; ++n) acc[m][n] = (f32x4){0.f, 0.f, 0.f, 0.f};

#pragma unroll
    for (int kk = 0; kk < 4; ++kk) {
        short8 b[2];
#pragma unroll
        for (int n = 0; n < 2; ++n) {
            const int col = cbase + n * 16 + lr;
            b[n] = *reinterpret_cast<const short8*>(WT + col * 128 + kk * 32 + lk);
        }
#pragma unroll
        for (int m = 0; m < 5; ++m) {
            const int row = m * 16 + lr;
            const int e = row * 128 + ((kk * 32 + lk) ^ ((row & 7) << 3));
            const short8 a = *reinterpret_cast<const short8*>(&Hs[e]);
#pragma unroll
            for (int n = 0; n < 2; ++n)
                acc[m][n] = __builtin_amdgcn_mfma_f32_16x16x32_bf16(a, b[n], acc[m][n], 0, 0, 0);
        }
    }

    const int row0 = blockIdx.x * 80;
    const int rq = (lane >> 4) * 4;
    if (mat == 0) {
#pragma unroll
        for (int m = 0; m < 5; ++m)
#pragma unroll
            for (int n = 0; n < 2; ++n) {
                const int col = cbase + n * 16 + lr;
#pragma unroll
                for (int q = 0; q < 4; ++q)
                    Y2pb[(size_t)(row0 + m * 16 + rq + q) * 64 + col] = f2b(acc[m][n][q]);
            }
    } else {
        float bias[2];
#pragma unroll
        for (int n = 0; n < 2; ++n) {
            const int col = cbase + n * 16 + lr;
            bias[n] = bs[col] + bp[col];
        }
#pragma unroll
        for (int m = 0; m < 5; ++m)
#pragma unroll
            for (int n = 0; n < 2; ++n) {
                const int col = cbase + n * 16 + lr;
#pragma unroll
                for (int q = 0; q < 4; ++q)
                    ACC2b[(size_t)(row0 + m * 16 + rq + q) * 64 + col] = f2b(acc[m][n][q] + bias[n]);
            }
    }
}

// ---------------------------------------------------------------------------
// agg2: H2b[i] = relu( ACC2b[i] + sum val_j * Y2pb[col_j] )   (bf16 out)
// 2 nodes per wave, 32 lanes/node; MLP=8.
// ---------------------------------------------------------------------------
__global__ __launch_bounds__(256) void k_agg2(
    const int* __restrict__ rowptr, const u32* __restrict__ ecv32,
    const u16* __restrict__ Y2pb, const u16* __restrict__ ACC2b,
    u16* __restrict__ H2b)
{
    const unsigned tid = blockIdx.x * 256u + threadIdx.x;
    const unsigned lane = tid & 63u;
    const unsigned i = (tid >> 6) * 2 + (lane >> 5);
    if (i >= N_NODES) return;
    const unsigned hl = lane & 31u;

    const int e0 = rowptr[i];
    const int e1 = rowptr[i + 1];

    const u32 s = reinterpret_cast<const u32*>(ACC2b)[i * 32 + hl];

    const u32* __restrict__ Yv = reinterpret_cast<const u32*>(Y2pb);

    float ax0 = 0.f, ay0 = 0.f, ax1 = 0.f, ay1 = 0.f;
    float ax2 = 0.f, ay2 = 0.f, ax3 = 0.f, ay3 = 0.f;
    int j = e0;
    for (; j + 7 < e1; j += 8) {
        u32 p[8], w[8];
#pragma unroll
        for (int q = 0; q < 8; ++q) p[q] = ecv32[j + q];
#pragma unroll
        for (int q = 0; q < 8; ++q) w[q] = Yv[(p[q] & 0xffffu) * 32 + hl];
#pragma unroll
        for (int q = 0; q < 8; ++q) {
            const float v = b2f((u16)(p[q] >> 16));
            if ((q & 3) == 0) { ax0 = fmaf(v, b2f((u16)(w[q] & 0xffffu)), ax0); ay0 = fmaf(v, b2f((u16)(w[q] >> 16)), ay0); }
            if ((q & 3) == 1) { ax1 = fmaf(v, b2f((u16)(w[q] & 0xffffu)), ax1); ay1 = fmaf(v, b2f((u16)(w[q] >> 16)), ay1); }
            if ((q & 3) == 2) { ax2 = fmaf(v, b2f((u16)(w[q] & 0xffffu)), ax2); ay2 = fmaf(v, b2f((u16)(w[q] >> 16)), ay2); }
            if ((q & 3) == 3) { ax3 = fmaf(v, b2f((u16)(w[q] & 0xffffu)), ax3); ay3 = fmaf(v, b2f((u16)(w[q] >> 16)), ay3); }
        }
    }
    for (; j + 3 < e1; j += 4) {
        const u32 p0 = ecv32[j], p1 = ecv32[j + 1], p2 = ecv32[j + 2], p3 = ecv32[j + 3];
        const u32 w0 = Yv[(p0 & 0xffffu) * 32 + hl];
        const u32 w1 = Yv[(p1 & 0xffffu) * 32 + hl];
        const u32 w2 = Yv[(p2 & 0xffffu) * 32 + hl];
        const u32 w3 = Yv[(p3 & 0xffffu) * 32 + hl];
        const float v0 = b2f((u16)(p0 >> 16)), v1 = b2f((u16)(p1 >> 16));
        const float v2 = b2f((u16)(p2 >> 16)), v3 = b2f((u16)(p3 >> 16));
        ax0 = fmaf(v0, b2f((u16)(w0 & 0xffffu)), ax0); ay0 = fmaf(v0, b2f((u16)(w0 >> 16)), ay0);
        ax1 = fmaf(v1, b2f((u16)(w1 & 0xffffu)), ax1); ay1 = fmaf(v1, b2f((u16)(w1 >> 16)), ay1);
        ax2 = fmaf(v2, b2f((u16)(w2 & 0xffffu)), ax2); ay2 = fmaf(v2, b2f((u16)(w2 >> 16)), ay2);
        ax3 = fmaf(v3, b2f((u16)(w3 & 0xffffu)), ax3); ay3 = fmaf(v3, b2f((u16)(w3 >> 16)), ay3);
    }
    for (; j < e1; ++j) {
        const u32 p = ecv32[j];
        const u32 w = Yv[(p & 0xffffu) * 32 + hl];
        const float v = b2f((u16)(p >> 16));
        ax0 = fmaf(v, b2f((u16)(w & 0xffffu)), ax0);
        ay0 = fmaf(v, b2f((u16)(w >> 16)), ay0);
    }
    const float ax = (ax0 + ax1) + (ax2 + ax3);
    const float ay = (ay0 + ay1) + (ay2 + ay3);

    const float h0 = fmaxf(b2f((u16)(s & 0xffffu)) + ax, 0.f);
    const float h1 = fmaxf(b2f((u16)(s >> 16)) + ay, 0.f);
    reinterpret_cast<u32*>(H2b)[i * 32 + hl] = (u32)f2b(h0) | ((u32)f2b(h1) << 16);
}

// ---------------------------------------------------------------------------
// edgedot: out[e] = sigmoid( dot(H2[row], H2[col]) )
// one THREAD per edge: 8x uint4 dual loads, 64-FMA register dot.
// ---------------------------------------------------------------------------
__global__ __launch_bounds__(256) void k_edgedot(
    const int* __restrict__ er, const int* __restrict__ ec,
    const u16* __restrict__ H2b, float* __restrict__ out)
{
    const int e = blockIdx.x * 256 + threadIdx.x;
    if (e >= N_EDGES) return;

    const int r = er[e];
    const int c = ec[e];

    const uint4* __restrict__ A = reinterpret_cast<const uint4*>(H2b + (size_t)r * 64);
    const uint4* __restrict__ B = reinterpret_cast<const uint4*>(H2b + (size_t)c * 64);

    float s0 = 0.f, s1 = 0.f, s2 = 0.f, s3 = 0.f;
#pragma unroll
    for (int k = 0; k < 8; ++k) {
        const uint4 a = A[k];
        const uint4 b = B[k];
        s0 = fmaf(b2f((u16)(a.x & 0xffffu)), b2f((u16)(b.x & 0xffffu)), s0);
        s1 = fmaf(b2f((u16)(a.x >> 16)),     b2f((u16)(b.x >> 16)),     s1);
        s2 = fmaf(b2f((u16)(a.y & 0xffffu)), b2f((u16)(b.y & 0xffffu)), s2);
        s3 = fmaf(b2f((u16)(a.y >> 16)),     b2f((u16)(b.y >> 16)),     s3);
        s0 = fmaf(b2f((u16)(a.z & 0xffffu)), b2f((u16)(b.z & 0xffffu)), s0);
        s1 = fmaf(b2f((u16)(a.z >> 16)),     b2f((u16)(b.z >> 16)),     s1);
        s2 = fmaf(b2f((u16)(a.w & 0xffffu)), b2f((u16)(b.w & 0xffffu)), s2);
        s3 = fmaf(b2f((u16)(a.w >> 16)),     b2f((u16)(b.w >> 16)),     s3);
    }
    const float p = (s0 + s1) + (s2 + s3);
    out[e] = 1.f / (1.f + expf(-p));
}

// ---------------------------------------------------------------------------
extern "C" void kernel_launch(void* const* d_in, const int* in_sizes, int n_in,
                              void* d_out, int out_size, void* d_ws, size_t ws_size,
                              hipStream_t stream)
{
    const float* X   = (const float*)d_in[0];
    const int*   er  = (const int*)d_in[1];
    const int*   ec  = (const int*)d_in[2];
    const float* ev  = (const float*)d_in[3];
    const float* Wp1 = (const float*)d_in[4];
    const float* bp1 = (const float*)d_in[5];
    const float* Ws1 = (const float*)d_in[6];
    const float* bs1 = (const float*)d_in[7];
    const float* Wp2 = (const float*)d_in[8];
    const float* bp2 = (const float*)d_in[9];
    const float* Ws2 = (const float*)d_in[10];
    const float* bs2 = (const float*)d_in[11];
    float* out = (float*)d_out;

    // workspace layout (float units from base):
    //   phase 1: ACC1b bf16 [0, 3.2M) | Y1pb bf16 [3.2M, 6.4M) | H1b bf16 [6.4M, 9.6M)
    //   phase 2 (reuses [0,4.8M)): Y2pb [0,1.6M) | ACC2b [1.6M,3.2M) | H2b [3.2M,4.8M)
    //   CSR at [9.6M,...): rp_base[50008] | bsum[64] | cur[256] | ecv32 u32[800k]
    //     | WT bufs | parted uint2[800k] (dedicated).
    //   cnt[50000] aliases ecv32 (dead before sort2).
    float* ws     = (float*)d_ws;
    u16*   ACC1b  = (u16*)ws;
    u16*   Y1pb   = (u16*)(ws + (size_t)3200000);
    u16*   H1b    = (u16*)(ws + (size_t)6400000);
    u16*   Y2pb   = (u16*)ws;
    u16*   ACC2b  = (u16*)(ws + (size_t)1600000);
    u16*   H2b    = (u16*)(ws + (size_t)3200000);

    int*  rp_base = (int*)(ws + (size_t)9600000);
    int*  rowptr  = rp_base + 3;          // rowptr+1 is 16B-aligned
    int*  bsum    = rp_base + 50008;      // 16B-aligned
    int*  cur     = bsum + 64;
    u32*  ecv32   = (u32*)(cur + 256);    // 16B-aligned
    int*  cnt     = (int*)ecv32;          // alias (dead before sort2)
    u16*  WT1p    = (u16*)(ecv32 + N_EDGES);
    u16*  WT1s    = WT1p + 128 * 128;
    u16*  WT2p    = WT1s + 128 * 128;
    u16*  WT2s    = WT2p + 64 * 128;
    uint2* parted = (uint2*)(WT2s + 64 * 128);   // 16B-aligned (even u16 count)

    const dim3 blk(256);
    const int node_waves  = (N_NODES * 64 + 255) / 256;        // 12500
    const int node2_waves = ((N_NODES / 2) * 64 + 255) / 256;  // 6250
    const int edge_thr    = (N_EDGES + 255) / 256;             // 3125
    const int scan_blocks = 49;
    const int part_blocks = (N_EDGES + PART_E - 1) / PART_E;   // 196
    const int fat_blocks  = GEMM_BLOCKS + part_blocks;         // 821

    // prep (zero + weight transpose) + CSR build
    k_prep    <<<241,         blk, 0, stream>>>(Wp1, Ws1, Wp2, Ws2,
                                                WT1p, WT1s, WT2p, WT2s, cnt);
    k_hist    <<<edge_thr,    blk, 0, stream>>>(er, cnt);
    k_scan1   <<<scan_blocks, blk, 0, stream>>>(cnt, rowptr, bsum);
    k_scan3   <<<scan_blocks, blk, 0, stream>>>(rowptr, bsum, cur);

    // layer-1 GEMM co-resident with edge partition (+pack)
    k_gemm1_part1<<<fat_blocks, blk, 0, stream>>>(X, WT1p, WT1s, bp1, bs1,
                                                  Y1pb, ACC1b, er, ec, ev, cur, parted);
    k_sort2   <<<NBUCKET,     blk, 0, stream>>>(rowptr, parted, ecv32);

    // layer 1 aggregation
    k_agg1 <<<node_waves,  blk, 0, stream>>>(rowptr, ecv32, Y1pb, ACC1b, H1b);

    // layer 2
    k_gemm2<<<GEMM_BLOCKS, blk, 0, stream>>>(H1b, WT2p, WT2s, bp2, bs2, Y2pb, ACC2b);
    k_agg2 <<<node2_waves, blk, 0, stream>>>(rowptr, ecv32, Y2pb, ACC2b, H2b);

    // edge scores
    k_edgedot<<<edge_thr, blk, 0, stream>>>(er, ec, H2b, out);
}